// Round 8
// baseline (194.527 us; speedup 1.0000x reference)
//
#include <hip/hip_runtime.h>
#include <hip/hip_cooperative_groups.h>

namespace cg = cooperative_groups;

// ---------------------------------------------------------------------------
// FEM assembly: dense stiffness (ndof x ndof) + residual (ndof).
// connect = [r, r+1, r+2] (mod N) => row 2n+d couples only to nodes n-2..n+2:
// a 10-wide (wrapped) band. Pipeline (2 graph nodes):
//   N0 hipMemsetAsync(d_out): 576 MB zero at fill speed (~87 us, the floor)
//   N1 ONE cooperative kernel (240 blocks x 256), 2 grid.sync()s:
//      ph0 zero cnt/mask
//      ph1 per-element 6x6 k -> kmat, start-node lists, traction, BC mask
//      ph2 per-row band gather from kmat (registers, static idx) -> one
//          contiguous 40B store per row; BC diag; last-wins resid fix
// Lesson r6/r7: runtime memset beats custom fills; the 6-dispatch serial
// chain (~62 us) is the remaining fat -> fuse it.
// ---------------------------------------------------------------------------

#define START_CAP 16   // elements per start-node; lambda~2, P(>16) ~ 1e-12

__global__ __launch_bounds__(256) void fused_kernel(
        const float* __restrict__ x, const float* __restrict__ y,
        const int* __restrict__ connect, const float* __restrict__ mat,
        const int* __restrict__ dl_elem, const int* __restrict__ dl_face,
        const float* __restrict__ dl_tx, const float* __restrict__ dl_ty,
        const int* __restrict__ fix_node, const int* __restrict__ fix_dof,
        const float* __restrict__ fix_val,
        float* __restrict__ kmat, int* __restrict__ cnt,
        int* __restrict__ mask, int* __restrict__ slist,
        float* __restrict__ stiff, float* __restrict__ resid,
        int nnode, int nelem, int ndload, int nfix) {
    cg::grid_group grid = cg::this_grid();
    const int tid = blockIdx.x * blockDim.x + threadIdx.x;
    const int nthreads = gridDim.x * blockDim.x;
    const int ndof = 2 * nnode;

    // ---- ph0: zero cnt + mask ----
    for (int i = tid; i < nnode + ndof; i += nthreads) {
        if (i < nnode) cnt[i] = 0;
        else           mask[i - nnode] = 0;
    }
    grid.sync();

    // ---- ph1: element stiffness -> kmat; start lists; traction; BC mask ----
    for (int e = tid; e < nelem; e += nthreads) {
        const int a = connect[3 * e + 0];
        const int b = connect[3 * e + 1];
        const int c = connect[3 * e + 2];

        const float xa = x[a], xb = x[b], xc = x[c];
        const float ya = y[a], yb = y[b], yc = y[c];

        const float den_a = (ya - yb) * (xc - xb) - (xa - xb) * (yc - yb);
        const float den_b = (yb - yc) * (xa - xc) - (xb - xc) * (ya - yc);
        const float den_c = (yc - ya) * (xb - xa) - (xc - xa) * (yb - ya);

        const float nax = -(yc - yb) / den_a;
        const float nay =  (xc - xb) / den_a;
        const float nbx = -(ya - yc) / den_b;
        const float nby =  (xa - xc) / den_b;
        const float ncx = -(yb - ya) / den_c;
        const float ncy =  (xb - xa) / den_c;

        const float area = 0.5f * fabsf((xb - xa) * (yc - ya) -
                                        (xc - xa) * (yb - ya));

        float nu, E;
        if (mat[e] > 0.5f) { nu = 0.33f; E = 69.0f; }   // aluminium
        else               { nu = 0.30f; E = 200.0f; }  // steel
        const float cc  = E / ((1.0f + nu) * (1.0f - 2.0f * nu));
        const float d00 = cc * (1.0f - nu);
        const float d01 = cc * nu;
        const float d22 = cc * (1.0f - 2.0f * nu) * 0.5f;

        const float B0[6] = { nax, 0.f, nbx, 0.f, ncx, 0.f };
        const float B1[6] = { 0.f, nay, 0.f, nby, 0.f, ncy };
        const float B2[6] = { nay, nax, nby, nbx, ncy, ncx };

        float* kp = kmat + (size_t)e * 36;
#pragma unroll
        for (int i = 0; i < 6; ++i) {
#pragma unroll
            for (int j = 0; j < 6; ++j) {
                const float C0j = d00 * B0[j] + d01 * B1[j];
                const float C1j = d01 * B0[j] + d00 * B1[j];
                const float C2j = d22 * B2[j];
                kp[i * 6 + j] = area * (B0[i] * C0j + B1[i] * C1j + B2[i] * C2j);
            }
        }
        // start-node list (element's first node = band anchor)
        const int slot = atomicAdd(&cnt[a], 1);
        if (slot < START_CAP) slist[a * START_CAP + slot] = e;
    }

    // traction loads -> resid (resid zeroed by the big memset node)
    for (int i = tid; i < ndload; i += nthreads) {
        const int e = dl_elem[i];
        const int f = dl_face[i];
        const int f2 = (f == 0) ? 1 : (f == 1 ? 2 : 0);   // pointer = [1,2,0]
        const int a = connect[3 * e + f];
        const int b = connect[3 * e + f2];
        const float dx = x[a] - x[b];
        const float dy = y[a] - y[b];
        const float hl = 0.5f * sqrtf(dx * dx + dy * dy);
        const float vx = dl_tx[i] * hl;
        const float vy = dl_ty[i] * hl;
        atomicAdd(&resid[2 * a + 0], vx);
        atomicAdd(&resid[2 * a + 1], vy);
        atomicAdd(&resid[2 * b + 0], vx);
        atomicAdd(&resid[2 * b + 1], vy);
    }

    // BC mask
    for (int i = tid; i < nfix; i += nthreads) {
        mask[2 * fix_node[i] + fix_dof[i]] = 1;
    }
    grid.sync();

    // ---- ph2: per-row band gather -> one contiguous 40B store; resid fix ----
    for (int row = tid; row < ndof; row += nthreads) {
        const int n = row >> 1;
        const int d = row & 1;

        float band[10];   // slot j = 2*dk + d', dk = partner - n + 2; all static idx
#pragma unroll
        for (int j = 0; j < 10; ++j) band[j] = 0.f;

        if (mask[row]) {
            band[4] = (d == 0) ? 1.f : 0.f;   // diag slot dk=2, d'=d
            band[5] = (d == 1) ? 1.f : 0.f;
        } else {
#pragma unroll
            for (int dd = 0; dd < 3; ++dd) {  // element start q = n - dd
                int q = n - dd;
                if (q < 0) q += nnode;
                int cq = cnt[q];
                if (cq > START_CAP) cq = START_CAP;
                for (int s = 0; s < cq; ++s) {
                    const int e = slist[q * START_CAP + s];
                    // k row i = 2*li + d with li = dd; partner p -> dk = p-dd+2
                    const float* kp = kmat + (size_t)e * 36 + (2 * dd + d) * 6;
                    band[2 * (2 - dd) + 0] += kp[0];
                    band[2 * (2 - dd) + 1] += kp[1];
                    band[2 * (3 - dd) + 0] += kp[2];
                    band[2 * (3 - dd) + 1] += kp[3];
                    band[2 * (4 - dd) + 0] += kp[4];
                    band[2 * (4 - dd) + 1] += kp[5];
                }
            }
        }

        float* rowp = stiff + (size_t)row * (size_t)ndof;
        if (n >= 2 && n < nnode - 2) {
            // contiguous cols 2n-4 .. 2n+5 (8B-aligned): 5 x float2
            float2* p2 = (float2*)(rowp + 2 * (n - 2));
#pragma unroll
            for (int j = 0; j < 5; ++j)
                p2[j] = make_float2(band[2 * j], band[2 * j + 1]);
        } else {
#pragma unroll
            for (int j = 0; j < 10; ++j) {
                int q2 = n + (j >> 1) - 2;
                if (q2 < 0)      q2 += nnode;
                if (q2 >= nnode) q2 -= nnode;
                rowp[2 * q2 + (j & 1)] = band[j];
            }
        }
    }

    // prescribed resid values, last-occurrence-wins (after traction: sync'd)
    for (int i = tid; i < nfix; ++i, i += nthreads - 1) {}  // (placeholder removed below)
    for (int i = tid; i < nfix; i += nthreads) {
        const int rw = 2 * fix_node[i] + fix_dof[i];
        bool last = true;
        for (int j = i + 1; j < nfix; ++j) {
            if (2 * fix_node[j] + fix_dof[j] == rw) { last = false; break; }
        }
        if (last) resid[rw] = fix_val[i];
    }
}

extern "C" void kernel_launch(void* const* d_in, const int* in_sizes, int n_in,
                              void* d_out, int out_size, void* d_ws, size_t ws_size,
                              hipStream_t stream) {
    const float* xcoord   = (const float*)d_in[0];
    const float* ycoord   = (const float*)d_in[1];
    const int*   connect  = (const int*)d_in[2];
    const float* emat     = (const float*)d_in[3];
    const int*   dl_elem  = (const int*)d_in[4];
    const int*   dl_face  = (const int*)d_in[5];
    const float* dl_tx    = (const float*)d_in[6];
    const float* dl_ty    = (const float*)d_in[7];
    const int*   fix_node = (const int*)d_in[8];
    const int*   fix_dof  = (const int*)d_in[9];
    const float* fix_val  = (const float*)d_in[10];

    int nnode  = in_sizes[0];
    int ndof   = 2 * nnode;
    int nelem  = in_sizes[3];
    int ndload = in_sizes[4];
    int nfix   = in_sizes[8];

    float* stiff = (float*)d_out;
    float* resid = stiff + (size_t)ndof * (size_t)ndof;

    // ws layout: kmat[nelem*36 f32] | cnt[nnode] | mask[ndof] | slist[nnode*16]
    float* kmat = (float*)d_ws;
    int*   cnt  = (int*)(kmat + (size_t)nelem * 36);
    int*   mask = cnt + nnode;
    int*   slist = mask + ndof;

    // N0: zero the entire output (stiff + resid) at memset/fill speed
    (void)hipMemsetAsync(d_out, 0, (size_t)out_size * sizeof(float), stream);

    // N1: everything else in one cooperative kernel
    void* args[] = {
        (void*)&xcoord, (void*)&ycoord, (void*)&connect, (void*)&emat,
        (void*)&dl_elem, (void*)&dl_face, (void*)&dl_tx, (void*)&dl_ty,
        (void*)&fix_node, (void*)&fix_dof, (void*)&fix_val,
        (void*)&kmat, (void*)&cnt, (void*)&mask, (void*)&slist,
        (void*)&stiff, (void*)&resid,
        (void*)&nnode, (void*)&nelem, (void*)&ndload, (void*)&nfix };
    (void)hipLaunchCooperativeKernel((const void*)fused_kernel,
                                     dim3(240), dim3(256), args, 0, stream);
}

// Round 9
// 155.003 us; speedup vs baseline: 1.2550x; 1.2550x over previous
//
#include <hip/hip_runtime.h>

// ---------------------------------------------------------------------------
// FEM assembly: dense stiffness (ndof x ndof) + residual (ndof).
// Structure: memset the 576 MB output (runtime fill = fastest known pure
// write, ~4.7 TB/s inferred), then TWO tiny kernels:
//   N1 setup (1 block): fixed-dof bitmap + diag=1 + last-wins resid values
//   N2 main: element scatter (atomicAdd, skipping fixed rows via bitmap)
//            + traction scatter (skipping fixed dofs)
// Equivalence to reference BC handling: reference zeroes fixed rows AFTER
// assembly and sets diag/resid AFTER traction. Since fixed-row contributions
// are simply discarded, never adding them (bitmap skip) + writing diag/resid
// up front yields identical output, with no post-pass over stiff.
// Lessons r1-r8: fill-speed write + minimal serial dispatch chain wins;
// coop-kernel fusion and custom fills both regressed.
// ---------------------------------------------------------------------------

// ws layout: bitmap[(ndof+31)/32] ints (1.5 KB)

__global__ __launch_bounds__(256) void setup_kernel(
        const int* __restrict__ fix_node, const int* __restrict__ fix_dof,
        const float* __restrict__ fix_val,
        unsigned int* __restrict__ bitmap,
        float* __restrict__ stiff, float* __restrict__ resid,
        int nfix, int nnode) {
    const int ndof = 2 * nnode;
    const int nw = (ndof + 31) >> 5;
    for (int i = threadIdx.x; i < nw; i += 256) bitmap[i] = 0u;
    __syncthreads();
    for (int i = threadIdx.x; i < nfix; i += 256) {
        const int rw = 2 * fix_node[i] + fix_dof[i];
        atomicOr(&bitmap[rw >> 5], 1u << (rw & 31));
        stiff[(size_t)rw * (size_t)ndof + rw] = 1.0f;  // dup fixes: same value
        // last-occurrence-wins (NumPy fancy-assignment semantics)
        bool last = true;
        for (int j = i + 1; j < nfix; ++j) {
            if (2 * fix_node[j] + fix_dof[j] == rw) { last = false; break; }
        }
        if (last) resid[rw] = fix_val[i];
    }
}

__global__ __launch_bounds__(256) void main_kernel(
        const float* __restrict__ x, const float* __restrict__ y,
        const int* __restrict__ connect, const float* __restrict__ mat,
        const int* __restrict__ dl_elem, const int* __restrict__ dl_face,
        const float* __restrict__ dl_tx, const float* __restrict__ dl_ty,
        const unsigned int* __restrict__ bitmap,
        float* __restrict__ stiff, float* __restrict__ resid,
        int nelem, int ndload, int nnode) {
    const int tid = blockIdx.x * 256 + threadIdx.x;
    const int ndof = 2 * nnode;

    if (tid < nelem) {
        const int e = tid;
        const int a = connect[3 * e + 0];
        const int b = connect[3 * e + 1];
        const int c = connect[3 * e + 2];

        const float xa = x[a], xb = x[b], xc = x[c];
        const float ya = y[a], yb = y[b], yc = y[c];

        const float den_a = (ya - yb) * (xc - xb) - (xa - xb) * (yc - yb);
        const float den_b = (yb - yc) * (xa - xc) - (xb - xc) * (ya - yc);
        const float den_c = (yc - ya) * (xb - xa) - (xc - xa) * (yb - ya);

        const float nax = -(yc - yb) / den_a;
        const float nay =  (xc - xb) / den_a;
        const float nbx = -(ya - yc) / den_b;
        const float nby =  (xa - xc) / den_b;
        const float ncx = -(yb - ya) / den_c;
        const float ncy =  (xb - xa) / den_c;

        const float area = 0.5f * fabsf((xb - xa) * (yc - ya) -
                                        (xc - xa) * (yb - ya));

        float nu, E;
        if (mat[e] > 0.5f) { nu = 0.33f; E = 69.0f; }   // aluminium
        else               { nu = 0.30f; E = 200.0f; }  // steel
        const float cc  = E / ((1.0f + nu) * (1.0f - 2.0f * nu));
        const float d00 = cc * (1.0f - nu);
        const float d01 = cc * nu;
        const float d22 = cc * (1.0f - 2.0f * nu) * 0.5f;

        const float B0[6] = { nax, 0.f, nbx, 0.f, ncx, 0.f };
        const float B1[6] = { 0.f, nay, 0.f, nby, 0.f, ncy };
        const float B2[6] = { nay, nax, nby, nbx, ncy, ncx };

        float C0[6], C1[6], C2[6];
#pragma unroll
        for (int j = 0; j < 6; ++j) {
            C0[j] = d00 * B0[j] + d01 * B1[j];
            C1[j] = d01 * B0[j] + d00 * B1[j];
            C2[j] = d22 * B2[j];
        }

        const int dof[6] = { 2 * a, 2 * a + 1, 2 * b, 2 * b + 1,
                             2 * c, 2 * c + 1 };

        // which of this element's 6 rows are fixed (skip those entirely)
        unsigned int rowfix = 0;
#pragma unroll
        for (int i = 0; i < 6; ++i) {
            rowfix |= ((bitmap[dof[i] >> 5] >> (dof[i] & 31)) & 1u) << i;
        }

#pragma unroll
        for (int i = 0; i < 6; ++i) {
            if ((rowfix >> i) & 1u) continue;   // fixed row: contribution dropped
            float* rowp = stiff + (size_t)dof[i] * (size_t)ndof;
#pragma unroll
            for (int j = 0; j < 6; ++j) {
                const float kij = area * (B0[i] * C0[j] + B1[i] * C1[j] +
                                          B2[i] * C2[j]);
                atomicAdd(rowp + dof[j], kij);
            }
        }
    }

    const int t2 = tid - nelem;
    if (t2 >= 0 && t2 < ndload) {
        const int e = dl_elem[t2];
        const int f = dl_face[t2];
        const int f2 = (f == 0) ? 1 : (f == 1 ? 2 : 0);   // pointer = [1,2,0]
        const int a = connect[3 * e + f];
        const int b = connect[3 * e + f2];
        const float dx = x[a] - x[b];
        const float dy = y[a] - y[b];
        const float hl = 0.5f * sqrtf(dx * dx + dy * dy);
        const float vx = dl_tx[t2] * hl;
        const float vy = dl_ty[t2] * hl;
        const int dofs[4] = { 2 * a, 2 * a + 1, 2 * b, 2 * b + 1 };
        const float vals[4] = { vx, vy, vx, vy };
#pragma unroll
        for (int k = 0; k < 4; ++k) {
            const int rw = dofs[k];
            const bool fixed = (bitmap[rw >> 5] >> (rw & 31)) & 1u;
            if (!fixed) atomicAdd(&resid[rw], vals[k]);   // fixed: set() wins anyway
        }
    }
}

extern "C" void kernel_launch(void* const* d_in, const int* in_sizes, int n_in,
                              void* d_out, int out_size, void* d_ws, size_t ws_size,
                              hipStream_t stream) {
    const float* xcoord   = (const float*)d_in[0];
    const float* ycoord   = (const float*)d_in[1];
    const int*   connect  = (const int*)d_in[2];
    const float* emat     = (const float*)d_in[3];
    const int*   dl_elem  = (const int*)d_in[4];
    const int*   dl_face  = (const int*)d_in[5];
    const float* dl_tx    = (const float*)d_in[6];
    const float* dl_ty    = (const float*)d_in[7];
    const int*   fix_node = (const int*)d_in[8];
    const int*   fix_dof  = (const int*)d_in[9];
    const float* fix_val  = (const float*)d_in[10];

    const int nnode  = in_sizes[0];
    const int ndof   = 2 * nnode;
    const int nelem  = in_sizes[3];
    const int ndload = in_sizes[4];
    const int nfix   = in_sizes[8];

    float* stiff = (float*)d_out;
    float* resid = stiff + (size_t)ndof * (size_t)ndof;
    unsigned int* bitmap = (unsigned int*)d_ws;

    // N0: zero the entire output (stiff + resid) — the 576 MB write floor
    (void)hipMemsetAsync(d_out, 0, (size_t)out_size * sizeof(float), stream);

    // N1: fixed-dof bitmap + unit diagonal + prescribed resid (1 block)
    setup_kernel<<<1, 256, 0, stream>>>(
        fix_node, fix_dof, fix_val, bitmap, stiff, resid, nfix, nnode);

    // N2: element scatter + traction, both skipping fixed dofs
    {
        const int total = nelem + ndload;
        const int blocks = (total + 255) / 256;
        main_kernel<<<blocks, 256, 0, stream>>>(
            xcoord, ycoord, connect, emat, dl_elem, dl_face, dl_tx, dl_ty,
            bitmap, stiff, resid, nelem, ndload, nnode);
    }
}

// Round 10
// 128.301 us; speedup vs baseline: 1.5162x; 1.2081x over previous
//
#include <hip/hip_runtime.h>

// ---------------------------------------------------------------------------
// FEM assembly: dense stiffness (ndof x ndof) + residual (ndof).
// Final structure (2 graph nodes):
//   N0 hipMemsetAsync(d_out): the 576 MB zero write. Measured across r1-r9:
//      in-graph pure-write runs ~4.4-4.6 TB/s (~130 us) regardless of writer
//      (runtime memset == custom writers); this is the structural floor.
//   N1 ONE kernel (50 blocks): per-block LDS fixed-dof bitmap (redundant
//      build, removes the grid-wide dependency), then by global tid:
//        [0,nelem)      element 6x6 scatter, skipping fixed rows (bitmap)
//        [.., +ndload)  traction atomics into resid, skipping fixed dofs
//        [.., +nfix)    diag=1 + last-occurrence-wins resid[rw]=fix_val
//      Race-free: scatter never touches fixed rows; dup diags store the
//      same 1.0; fixed resid never receives adds.
// Equivalence to reference: dropping fixed-row contributions == zeroing the
// row afterwards; skipping traction adds on fixed dofs == set() overwriting.
// ---------------------------------------------------------------------------

__global__ __launch_bounds__(256) void fused_kernel(
        const float* __restrict__ x, const float* __restrict__ y,
        const int* __restrict__ connect, const float* __restrict__ mat,
        const int* __restrict__ dl_elem, const int* __restrict__ dl_face,
        const float* __restrict__ dl_tx, const float* __restrict__ dl_ty,
        const int* __restrict__ fix_node, const int* __restrict__ fix_dof,
        const float* __restrict__ fix_val,
        float* __restrict__ stiff, float* __restrict__ resid,
        int nelem, int ndload, int nfix, int nnode) {
    __shared__ unsigned int bm[512];          // fixed-dof bitmap, ndof<=16384
    const int ndof = 2 * nnode;
    const int nw = (ndof + 31) >> 5;

    // redundant per-block bitmap build (200 fixes, L2-hot)
    for (int i = threadIdx.x; i < nw; i += 256) bm[i] = 0u;
    __syncthreads();
    for (int i = threadIdx.x; i < nfix; i += 256) {
        const int rw = 2 * fix_node[i] + fix_dof[i];
        atomicOr(&bm[rw >> 5], 1u << (rw & 31));
    }
    __syncthreads();

    const int tid = blockIdx.x * 256 + threadIdx.x;

    if (tid < nelem) {
        const int e = tid;
        const int a = connect[3 * e + 0];
        const int b = connect[3 * e + 1];
        const int c = connect[3 * e + 2];

        const float xa = x[a], xb = x[b], xc = x[c];
        const float ya = y[a], yb = y[b], yc = y[c];

        const float den_a = (ya - yb) * (xc - xb) - (xa - xb) * (yc - yb);
        const float den_b = (yb - yc) * (xa - xc) - (xb - xc) * (ya - yc);
        const float den_c = (yc - ya) * (xb - xa) - (xc - xa) * (yb - ya);

        const float nax = -(yc - yb) / den_a;
        const float nay =  (xc - xb) / den_a;
        const float nbx = -(ya - yc) / den_b;
        const float nby =  (xa - xc) / den_b;
        const float ncx = -(yb - ya) / den_c;
        const float ncy =  (xb - xa) / den_c;

        const float area = 0.5f * fabsf((xb - xa) * (yc - ya) -
                                        (xc - xa) * (yb - ya));

        float nu, E;
        if (mat[e] > 0.5f) { nu = 0.33f; E = 69.0f; }   // aluminium
        else               { nu = 0.30f; E = 200.0f; }  // steel
        const float cc  = E / ((1.0f + nu) * (1.0f - 2.0f * nu));
        const float d00 = cc * (1.0f - nu);
        const float d01 = cc * nu;
        const float d22 = cc * (1.0f - 2.0f * nu) * 0.5f;

        const float B0[6] = { nax, 0.f, nbx, 0.f, ncx, 0.f };
        const float B1[6] = { 0.f, nay, 0.f, nby, 0.f, ncy };
        const float B2[6] = { nay, nax, nby, nbx, ncy, ncx };

        float C0[6], C1[6], C2[6];
#pragma unroll
        for (int j = 0; j < 6; ++j) {
            C0[j] = d00 * B0[j] + d01 * B1[j];
            C1[j] = d01 * B0[j] + d00 * B1[j];
            C2[j] = d22 * B2[j];
        }

        const int dof[6] = { 2 * a, 2 * a + 1, 2 * b, 2 * b + 1,
                             2 * c, 2 * c + 1 };

#pragma unroll
        for (int i = 0; i < 6; ++i) {
            const bool fixed = (bm[dof[i] >> 5] >> (dof[i] & 31)) & 1u;
            if (fixed) continue;            // fixed row: contribution dropped
            float* rowp = stiff + (size_t)dof[i] * (size_t)ndof;
#pragma unroll
            for (int j = 0; j < 6; ++j) {
                const float kij = area * (B0[i] * C0[j] + B1[i] * C1[j] +
                                          B2[i] * C2[j]);
                atomicAdd(rowp + dof[j], kij);
            }
        }
        return;
    }

    const int t2 = tid - nelem;
    if (t2 < ndload) {
        const int e = dl_elem[t2];
        const int f = dl_face[t2];
        const int f2 = (f == 0) ? 1 : (f == 1 ? 2 : 0);   // pointer = [1,2,0]
        const int a = connect[3 * e + f];
        const int b = connect[3 * e + f2];
        const float dx = x[a] - x[b];
        const float dy = y[a] - y[b];
        const float hl = 0.5f * sqrtf(dx * dx + dy * dy);
        const float vx = dl_tx[t2] * hl;
        const float vy = dl_ty[t2] * hl;
        const int dofs[4] = { 2 * a, 2 * a + 1, 2 * b, 2 * b + 1 };
        const float vals[4] = { vx, vy, vx, vy };
#pragma unroll
        for (int k = 0; k < 4; ++k) {
            const int rw = dofs[k];
            const bool fixed = (bm[rw >> 5] >> (rw & 31)) & 1u;
            if (!fixed) atomicAdd(&resid[rw], vals[k]);  // fixed: set() wins
        }
        return;
    }

    const int t3 = t2 - ndload;
    if (t3 < nfix) {
        const int rw = 2 * fix_node[t3] + fix_dof[t3];
        stiff[(size_t)rw * (size_t)ndof + rw] = 1.0f;    // dups: same value
        // last-occurrence-wins (NumPy fancy-assignment semantics)
        bool last = true;
        for (int j = t3 + 1; j < nfix; ++j) {
            if (2 * fix_node[j] + fix_dof[j] == rw) { last = false; break; }
        }
        if (last) resid[rw] = fix_val[t3];
    }
}

extern "C" void kernel_launch(void* const* d_in, const int* in_sizes, int n_in,
                              void* d_out, int out_size, void* d_ws, size_t ws_size,
                              hipStream_t stream) {
    const float* xcoord   = (const float*)d_in[0];
    const float* ycoord   = (const float*)d_in[1];
    const int*   connect  = (const int*)d_in[2];
    const float* emat     = (const float*)d_in[3];
    const int*   dl_elem  = (const int*)d_in[4];
    const int*   dl_face  = (const int*)d_in[5];
    const float* dl_tx    = (const float*)d_in[6];
    const float* dl_ty    = (const float*)d_in[7];
    const int*   fix_node = (const int*)d_in[8];
    const int*   fix_dof  = (const int*)d_in[9];
    const float* fix_val  = (const float*)d_in[10];

    const int nnode  = in_sizes[0];
    const int ndof   = 2 * nnode;
    const int nelem  = in_sizes[3];
    const int ndload = in_sizes[4];
    const int nfix   = in_sizes[8];

    float* stiff = (float*)d_out;
    float* resid = stiff + (size_t)ndof * (size_t)ndof;

    // N0: the 576 MB zero write (structural floor, ~130 us in-graph)
    (void)hipMemsetAsync(d_out, 0, (size_t)out_size * sizeof(float), stream);

    // N1: everything else in one ordinary kernel
    {
        const int total = nelem + ndload + nfix;
        const int blocks = (total + 255) / 256;
        fused_kernel<<<blocks, 256, 0, stream>>>(
            xcoord, ycoord, connect, emat, dl_elem, dl_face, dl_tx, dl_ty,
            fix_node, fix_dof, fix_val, stiff, resid,
            nelem, ndload, nfix, nnode);
    }
}